// Round 1
// baseline (204.122 us; speedup 1.0000x reference)
//
#include <hip/hip_runtime.h>
#include <math.h>

#define FHW   32
#define NA    9
#define NBOX  9216          // 32*32*9
#define C1    256
#define C2    512
#define KTOT  2304          // 256*9
#define KS    8             // split-K factor
#define KCH   (KTOT / KS)   // 288
#define CAP   64            // max stored in-neighbors per box

struct AnchorWH { float w[NA]; float h[NA]; };

// ---------------- workspace layout (bytes, all 256-aligned) ----------------
#define FP_OFF    0u                      // padded feature 256*34*34 f32 = 1,183,744
#define WT_OFF    1183744u                // transposed weights 2304*512 f32 = 4,718,592
#define HP_OFF    5902336u                // split-K partials 8*1024*512 f32 = 16,777,216
#define BOX_OFF   22679552u               // boxes 9216*4 f32
#define SC_OFF    22827008u               // scores 9216 f32
#define VL_OFF    22863872u               // vlist 9216 u32
#define DEG_OFF   22900736u               // deg 9216 u32
#define ADJ_OFF   22937600u               // adj 9216*CAP u16 = 1,179,648
#define KEEP_OFF  24117248u               // keep 9216 u32
#define NV_OFF    24154112u               // valid count u32

// ---------------------------------------------------------------------------
// Kernel 1: zero-pad feature map into Fp[256][34][34]; zero deg[] and Nv.
// ---------------------------------------------------------------------------
__global__ __launch_bounds__(256) void k_prep(const float* __restrict__ fin,
                                              float* __restrict__ Fp,
                                              unsigned int* __restrict__ deg,
                                              unsigned int* __restrict__ nv) {
    int idx = blockIdx.x * 256 + threadIdx.x;
    if (idx < 256 * 34 * 34) {
        int c   = idx / 1156;
        int rem = idx - c * 1156;
        int yy  = rem / 34;
        int xx  = rem - yy * 34;
        float v = 0.f;
        if (yy >= 1 && yy <= 32 && xx >= 1 && xx <= 32)
            v = fin[c * 1024 + (yy - 1) * 32 + (xx - 1)];
        Fp[idx] = v;
    }
    if (idx < NBOX) deg[idx] = 0u;
    if (idx == 0)   *nv = 0u;
}

// ---------------------------------------------------------------------------
// Kernel 2: transpose conv1_w [512][2304] -> Wt [2304][512] (coalesced GEMM-B)
// ---------------------------------------------------------------------------
__global__ __launch_bounds__(256) void k_tr(const float* __restrict__ w1,
                                            float* __restrict__ Wt) {
    __shared__ float tile[32][33];
    int k0  = blockIdx.x * 32;   // 72 tiles
    int oc0 = blockIdx.y * 32;   // 16 tiles
    int t   = threadIdx.x;
    int r0 = t >> 5, c = t & 31;
    #pragma unroll
    for (int i = 0; i < 4; ++i) {
        int r = r0 + 8 * i;                       // oc-local
        tile[r][c] = w1[(oc0 + r) * KTOT + k0 + c];
    }
    __syncthreads();
    #pragma unroll
    for (int i = 0; i < 4; ++i) {
        int kk = r0 + 8 * i;                      // k-local
        Wt[(k0 + kk) * C2 + oc0 + c] = tile[c][kk];
    }
}

// ---------------------------------------------------------------------------
// Kernel 3: split-K fp32 GEMM. h_part[ks][p][oc] = sum_{k in chunk} A[p][k]*W[oc][k]
// A[p][k] gathered from padded feature (im2col on the fly), k = c*9+ky*3+kx.
// BM=BN=128, BK=16, 256 threads, 8x8 microtile.
// ---------------------------------------------------------------------------
__global__ __launch_bounds__(256) void k_gemm(const float* __restrict__ Fp,
                                              const float* __restrict__ Wt,
                                              float* __restrict__ hp) {
    const int p0  = blockIdx.x * 128;     // 8
    const int oc0 = blockIdx.y * 128;     // 4
    const int ks  = blockIdx.z;           // 8
    const int k0b = ks * KCH;
    const int t   = threadIdx.x;
    const int ty  = t >> 4, tx = t & 15;

    __shared__ float As[16][128];
    __shared__ float Bs[16][128];

    float acc[8][8];
    #pragma unroll
    for (int r = 0; r < 8; ++r)
        #pragma unroll
        for (int c = 0; c < 8; ++c) acc[r][c] = 0.f;

    for (int kt = 0; kt < KCH; kt += 16) {
        #pragma unroll
        for (int i = 0; i < 8; ++i) {             // A tile: 16x128
            int e  = t + 256 * i;
            int kk = e >> 7, pp = e & 127;
            int k  = k0b + kt + kk;
            int c  = k / 9;
            int kap = k - c * 9;
            int dy = kap / 3;
            int dx = kap - dy * 3;
            int p  = p0 + pp;
            int y  = p >> 5, x = p & 31;
            As[kk][pp] = Fp[(c * 34 + y + dy) * 34 + x + dx];
        }
        #pragma unroll
        for (int i = 0; i < 8; ++i) {             // B tile: 16x128
            int e  = t + 256 * i;
            int kk = e >> 7, j = e & 127;
            Bs[kk][j] = Wt[(k0b + kt + kk) * C2 + oc0 + j];
        }
        __syncthreads();
        #pragma unroll
        for (int kk = 0; kk < 16; ++kk) {
            float a[8], b[8];
            *(float4*)&a[0] = *(const float4*)&As[kk][ty * 8];
            *(float4*)&a[4] = *(const float4*)&As[kk][ty * 8 + 4];
            *(float4*)&b[0] = *(const float4*)&Bs[kk][tx * 8];
            *(float4*)&b[4] = *(const float4*)&Bs[kk][tx * 8 + 4];
            #pragma unroll
            for (int r = 0; r < 8; ++r)
                #pragma unroll
                for (int c = 0; c < 8; ++c) acc[r][c] += a[r] * b[c];
        }
        __syncthreads();
    }
    #pragma unroll
    for (int r = 0; r < 8; ++r) {
        int p = p0 + ty * 8 + r;
        float* dst = hp + ((ks * 1024 + p) * C2 + oc0 + tx * 8);
        *(float4*)dst       = *(float4*)&acc[r][0];
        *(float4*)(dst + 4) = *(float4*)&acc[r][4];
    }
}

// ---------------------------------------------------------------------------
// Kernel 4: per-pixel heads: reduce split-K + bias + relu, 45 dot products,
// sigmoid, anchor decode, clip, valid mask, compact valid list.
// One block per pixel (1024 blocks, 256 threads).
// ---------------------------------------------------------------------------
__global__ __launch_bounds__(256) void k_heads(const float* __restrict__ hp,
                                               const float* __restrict__ b1,
                                               const float* __restrict__ w2,
                                               const float* __restrict__ b2,
                                               const float* __restrict__ w3,
                                               const float* __restrict__ b3,
                                               float* __restrict__ boxes,
                                               float* __restrict__ scoresG,
                                               unsigned int* __restrict__ nv,
                                               unsigned int* __restrict__ vlist,
                                               AnchorWH awh) {
    const int p = blockIdx.x;
    const int t = threadIdx.x;
    __shared__ float hrow[C2];
    __shared__ float arr[45];

    #pragma unroll
    for (int i = 0; i < 2; ++i) {
        int c = t + 256 * i;
        float s = b1[c];
        #pragma unroll
        for (int ks = 0; ks < KS; ++ks) s += hp[(ks * 1024 + p) * C2 + c];
        hrow[c] = fmaxf(s, 0.f);
    }
    __syncthreads();

    const int w = t >> 6, lane = t & 63;
    float h8[8];
    #pragma unroll
    for (int i = 0; i < 8; ++i) h8[i] = hrow[lane + 64 * i];

    for (int j = w; j < 45; j += 4) {
        const float* wp = (j < 9) ? (w2 + j * C2) : (w3 + (j - 9) * C2);
        float s = 0.f;
        #pragma unroll
        for (int i = 0; i < 8; ++i) s += h8[i] * wp[lane + 64 * i];
        #pragma unroll
        for (int d = 1; d < 64; d <<= 1) s += __shfl_xor(s, d, 64);
        if (lane == 0) arr[j] = s;
    }
    __syncthreads();

    if (t < NA) {
        int a = t;
        float logit = arr[a] + b2[a];
        float score = 1.f / (1.f + expf(-logit));
        float o0 = arr[9 + a * 4 + 0] + b3[a * 4 + 0];
        float o1 = arr[9 + a * 4 + 1] + b3[a * 4 + 1];
        float o2 = arr[9 + a * 4 + 2] + b3[a * 4 + 2];
        float o3 = arr[9 + a * 4 + 3] + b3[a * 4 + 3];
        int y = p >> 5, x = p & 31;
        float ax = (x + 0.5f) * 16.f, ay = (y + 0.5f) * 16.f;
        float aw = awh.w[a], ah = awh.h[a];
        float cx = ax + o0 * aw;
        float cy = ay + o1 * ah;
        float bw = aw * expf(o2);
        float bh = ah * expf(o3);
        float x1 = fminf(fmaxf(cx - bw * 0.5f, 0.f), 512.f);
        float y1 = fminf(fmaxf(cy - bh * 0.5f, 0.f), 512.f);
        float x2 = fminf(fmaxf(cx + bw * 0.5f, 0.f), 512.f);
        float y2 = fminf(fmaxf(cy + bh * 0.5f, 0.f), 512.f);
        int n = p * 9 + a;
        float4 bx4; bx4.x = x1; bx4.y = y1; bx4.z = x2; bx4.w = y2;
        ((float4*)boxes)[n] = bx4;
        scoresG[n] = score;
        bool valid = (x2 - x1 >= 0.001f) && (y2 - y1 >= 0.001f) && (score >= 0.5f);
        if (valid) {
            unsigned int ci = atomicAdd(nv, 1u);
            vlist[ci] = (unsigned int)n;
        }
    }
}

// ---------------------------------------------------------------------------
// Kernel 5: sparse adjacency among valid boxes. For each pair with IoU>0.7,
// store the higher-priority node (score desc, orig-index asc tie-break ==
// stable argsort(-s)) into the lower-priority node's in-neighbor list.
// Triangular 128x128 tiling over the compacted valid list.
// ---------------------------------------------------------------------------
__global__ __launch_bounds__(256) void k_adj(const unsigned int* __restrict__ nvp,
                                             const unsigned int* __restrict__ vlist,
                                             const float* __restrict__ boxes,
                                             const float* __restrict__ scoresG,
                                             unsigned int* __restrict__ deg,
                                             unsigned short* __restrict__ adj) {
    const int Nv = (int)*nvp;
    int b = blockIdx.x;
    // triangular index -> (tu <= tv)
    int tv = (int)(sqrtf(2.f * b + 0.25f) - 0.5f);
    while ((tv + 1) * (tv + 2) / 2 <= b) tv++;
    while (tv * (tv + 1) / 2 > b) tv--;
    int tu = b - tv * (tv + 1) / 2;
    if (tv * 128 >= Nv) return;

    __shared__ float4 ub[128], vb[128];
    __shared__ float  us[128], vs[128];
    __shared__ int    uo[128], vo[128];
    int t = threadIdx.x;
    if (t < 128) {
        int gi = tu * 128 + t;
        if (gi < Nv) { int n = (int)vlist[gi]; ub[t] = ((const float4*)boxes)[n]; us[t] = scoresG[n]; uo[t] = n; }
        else us[t] = -1.f;
    } else {
        int tt = t - 128;
        int gj = tv * 128 + tt;
        if (gj < Nv) { int n = (int)vlist[gj]; vb[tt] = ((const float4*)boxes)[n]; vs[tt] = scoresG[n]; vo[tt] = n; }
        else vs[tt] = -1.f;
    }
    __syncthreads();

    for (int s = 0; s < 64; ++s) {
        int q  = t + 256 * s;          // 16384 pairs
        int i  = q >> 7, jj = q & 127;
        if (tu == tv && i >= jj) continue;
        float su = us[i], sv = vs[jj];
        if (su < 0.f || sv < 0.f) continue;
        float4 bu = ub[i], bv = vb[jj];
        float au = (bu.z - bu.x) * (bu.w - bu.y);
        float av = (bv.z - bv.x) * (bv.w - bv.y);
        float ix1 = fmaxf(bu.x, bv.x), iy1 = fmaxf(bu.y, bv.y);
        float ix2 = fminf(bu.z, bv.z), iy2 = fminf(bu.w, bv.w);
        float inter = fmaxf(ix2 - ix1, 0.f) * fmaxf(iy2 - iy1, 0.f);
        float uni = au + av - inter;
        float iou = inter / fmaxf(uni, 1e-9f);
        if (iou > 0.7f) {
            int gi = tu * 128 + i, gj = tv * 128 + jj;
            bool uHigh = (su > sv) || (su == sv && uo[i] < vo[jj]);
            int lower = uHigh ? gj : gi;
            int upper = uHigh ? gi : gj;
            unsigned int slot = atomicAdd(&deg[lower], 1u);
            if (slot < CAP) adj[lower * CAP + slot] = (unsigned short)upper;
        }
    }
}

// ---------------------------------------------------------------------------
// Kernel 6: single-block MIS peeling == exact greedy NMS.
// state: 0 undecided, 1 kept, 2 suppressed. Monotone updates -> races benign.
// ---------------------------------------------------------------------------
__global__ __launch_bounds__(1024) void k_peel(const unsigned int* __restrict__ nvp,
                                               const unsigned int* __restrict__ vlist,
                                               const unsigned int* __restrict__ deg,
                                               const unsigned short* __restrict__ adj,
                                               unsigned int* __restrict__ keep) {
    __shared__ unsigned char st[NBOX];
    __shared__ int changed;
    const int t = threadIdx.x;
    const int Nv = (int)*nvp;
    for (int n = t; n < NBOX; n += 1024) keep[n] = 0u;
    for (int i = t; i < Nv; i += 1024) st[i] = 0;
    __syncthreads();

    for (int round = 0; round < 512; ++round) {
        if (t == 0) changed = 0;
        __syncthreads();
        bool any = false;
        for (int i = t; i < Nv; i += 1024) {
            if (st[i] == 0) {
                int d = (int)deg[i]; if (d > CAP) d = CAP;
                bool kseen = false, useen = false;
                for (int s = 0; s < d; ++s) {
                    unsigned char v = st[adj[i * CAP + s]];
                    kseen |= (v == 1);
                    useen |= (v == 0);
                }
                if (kseen)      { st[i] = 2; any = true; }
                else if (!useen){ st[i] = 1; any = true; }
            }
        }
        if (any) changed = 1;
        __syncthreads();
        int c = changed;
        __syncthreads();
        if (!c) break;
    }
    for (int i = t; i < Nv; i += 1024)
        if (st[i] == 1) keep[vlist[i]] = 1u;
}

// ---------------------------------------------------------------------------
// Kernel 7: write output (9216 x 5): boxes*keep, scores*keep.
// ---------------------------------------------------------------------------
__global__ __launch_bounds__(256) void k_out(const float* __restrict__ boxes,
                                             const float* __restrict__ scoresG,
                                             const unsigned int* __restrict__ keep,
                                             float* __restrict__ out) {
    int n = blockIdx.x * 256 + threadIdx.x;
    if (n >= NBOX) return;
    float4 b = ((const float4*)boxes)[n];
    bool k = keep[n] != 0u;
    out[n * 5 + 0] = k ? b.x : 0.f;
    out[n * 5 + 1] = k ? b.y : 0.f;
    out[n * 5 + 2] = k ? b.z : 0.f;
    out[n * 5 + 3] = k ? b.w : 0.f;
    out[n * 5 + 4] = k ? scoresG[n] : 0.f;
}

// ---------------------------------------------------------------------------
extern "C" void kernel_launch(void* const* d_in, const int* in_sizes, int n_in,
                              void* d_out, int out_size, void* d_ws, size_t ws_size,
                              hipStream_t stream) {
    const float* fin = (const float*)d_in[0];
    const float* w1  = (const float*)d_in[1];
    const float* b1  = (const float*)d_in[2];
    const float* w2  = (const float*)d_in[3];
    const float* b2  = (const float*)d_in[4];
    const float* w3  = (const float*)d_in[5];
    const float* b3  = (const float*)d_in[6];
    float* out = (float*)d_out;

    char* ws = (char*)d_ws;
    float*          Fp    = (float*)(ws + FP_OFF);
    float*          Wt    = (float*)(ws + WT_OFF);
    float*          hp    = (float*)(ws + HP_OFF);
    float*          boxes = (float*)(ws + BOX_OFF);
    float*          sc    = (float*)(ws + SC_OFF);
    unsigned int*   vlist = (unsigned int*)(ws + VL_OFF);
    unsigned int*   deg   = (unsigned int*)(ws + DEG_OFF);
    unsigned short* adj   = (unsigned short*)(ws + ADJ_OFF);
    unsigned int*   keep  = (unsigned int*)(ws + KEEP_OFF);
    unsigned int*   nv    = (unsigned int*)(ws + NV_OFF);

    AnchorWH awh;
    {
        const double sizes[3]  = {32.0, 64.0, 128.0};
        const double ratios[3] = {0.5, 1.0, 2.0};
        for (int si = 0; si < 3; ++si)
            for (int ri = 0; ri < 3; ++ri) {
                awh.w[si * 3 + ri] = (float)(sizes[si] / sqrt(ratios[ri]));
                awh.h[si * 3 + ri] = (float)(sizes[si] * sqrt(ratios[ri]));
            }
    }

    k_prep<<<dim3((256 * 34 * 34 + 255) / 256), 256, 0, stream>>>(fin, Fp, deg, nv);
    k_tr<<<dim3(72, 16), 256, 0, stream>>>(w1, Wt);
    k_gemm<<<dim3(8, 4, KS), 256, 0, stream>>>(Fp, Wt, hp);
    k_heads<<<dim3(1024), 256, 0, stream>>>(hp, b1, w2, b2, w3, b3, boxes, sc, nv, vlist, awh);
    k_adj<<<dim3(72 * 73 / 2), 256, 0, stream>>>(nv, vlist, boxes, sc, deg, adj);
    k_peel<<<dim3(1), 1024, 0, stream>>>(nv, vlist, deg, adj, keep);
    k_out<<<dim3((NBOX + 255) / 256), 256, 0, stream>>>(boxes, sc, keep, out);
}